// Round 11
// baseline (287.230 us; speedup 1.0000x reference)
//
#include <hip/hip_runtime.h>
#include <stdint.h>

// ---------------- problem constants ----------------
#define B2      192          // 16 * MAX_FRAMES
#define NTOK    50           // tokens per frame-batch
#define ROWS    9600         // B2 * NTOK
#define D_EMB   512
#define C_DIM   256
#define HD      128          // head dim
#define NSAMP   500
#define TOPKK   12
#define NSPA    48           // 50 - SEL_DIM
#define NSAMP_T 96000        // B2 * NSAMP
#define NOISE_OFF 61953536ull
#define NOISE_BYTES 18432000ull   // 96000*48*4
#define WS_NEED (NOISE_OFF + NOISE_BYTES)
#define NCNT    (B2 * TOPKK * NSPA)   // 110592 ints

typedef short short8 __attribute__((ext_vector_type(8)));
typedef float f32x4  __attribute__((ext_vector_type(4)));

__device__ __forceinline__ float gelu_f(float x) {
    return 0.5f * x * (1.0f + erff(x * 0.7071067811865476f));
}
__device__ __forceinline__ uint16_t f2bf(float x) {   // RNE fp32->bf16
    uint32_t u = __float_as_uint(x);
    return (uint16_t)((u + 0x7fffu + ((u >> 16) & 1u)) >> 16);
}
__device__ __forceinline__ float bf2f(uint16_t b) {
    return __uint_as_float(((uint32_t)b) << 16);
}
// swizzled A-operand halfword index (frag-contiguous MFMA layout)
__device__ __forceinline__ size_t swzA(int m, int k, int K) {
    return ((size_t)(m >> 4) * (K >> 5) + (k >> 5)) * 512
         + (size_t)((((k >> 3) & 3) * 16 + (m & 15)) * 8 + (k & 7));
}

// ---------------- JAX threefry2x32 with key (0,1) ----------------
__device__ __forceinline__ uint32_t rotl32(uint32_t x, int r) {
    return (x << r) | (x >> (32 - r));
}
__device__ __forceinline__ void threefry01(uint32_t& x0, uint32_t& x1) {
    const uint32_t ks0 = 0u, ks1 = 1u, ks2 = 0x1BD11BDBu;
    x0 += ks0; x1 += ks1;
#define TFR(r) { x0 += x1; x1 = rotl32(x1, r); x1 ^= x0; }
    TFR(13) TFR(15) TFR(26) TFR(6)  x0 += ks1; x1 += ks2 + 1u;
    TFR(17) TFR(29) TFR(16) TFR(24) x0 += ks2; x1 += ks0 + 2u;
    TFR(13) TFR(15) TFR(26) TFR(6)  x0 += ks0; x1 += ks1 + 3u;
    TFR(17) TFR(29) TFR(16) TFR(24) x0 += ks1; x1 += ks2 + 4u;
    TFR(13) TFR(15) TFR(26) TFR(6)  x0 += ks2; x1 += ks0 + 5u;
#undef TFR
}

__device__ __forceinline__ float erfinv_xla(float x) {
    float w = -log1pf(-x * x);
    float p;
    if (w < 5.0f) {
        w -= 2.5f;
        p = 2.81022636e-08f;
        p = fmaf(p, w, 3.43273939e-07f);
        p = fmaf(p, w, -3.5233877e-06f);
        p = fmaf(p, w, -4.39150654e-06f);
        p = fmaf(p, w, 0.00021858087f);
        p = fmaf(p, w, -0.00125372503f);
        p = fmaf(p, w, -0.00417768164f);
        p = fmaf(p, w, 0.246640727f);
        p = fmaf(p, w, 1.50140941f);
    } else {
        w = sqrtf(w) - 3.0f;
        p = -0.000200214257f;
        p = fmaf(p, w, 0.000100950558f);
        p = fmaf(p, w, 0.00134934322f);
        p = fmaf(p, w, -0.00367342844f);
        p = fmaf(p, w, 0.00573950773f);
        p = fmaf(p, w, -0.0076224613f);
        p = fmaf(p, w, 0.00943887047f);
        p = fmaf(p, w, 1.00167406f);
        p = fmaf(p, w, 2.83297682f);
    }
    return p * x;
}

__device__ __forceinline__ float bits_to_normal(uint32_t bits) {
    float f = __uint_as_float((bits >> 9) | 0x3f800000u) - 1.0f;
    float u = f * 2.0f + (-0.99999994039535522461f);
    u = fmaxf(-0.99999994039535522461f, u);
    return 1.4142135623730951f * erfinv_xla(u);
}

// ---------------- fused LN + weight swizzle (one launch) ----------------
// blocks 0..2399: LayerNorm rows; 2400..2623: weight swizzle.
__global__ __launch_bounds__(256) void prep_kernel(const float* __restrict__ x,
                                                   const float* __restrict__ g,
                                                   const float* __restrict__ b,
                                                   short* __restrict__ xh,
                                                   short* __restrict__ xl,
                                                   const float* __restrict__ w_in, const float* __restrict__ wq,
                                                   const float* __restrict__ wk, const float* __restrict__ wv,
                                                   const float* __restrict__ wo, const float* __restrict__ w1,
                                                   short* win_hi, short* win_lo, short* wq_hi, short* wq_lo,
                                                   short* wk_hi, short* wk_lo, short* wv_hi, short* wv_lo,
                                                   short* wo_hi, short* wo_lo, short* w1a_hi, short* w1a_lo) {
    if (blockIdx.x < 2400) {
        int row  = blockIdx.x * 4 + (threadIdx.x >> 6);
        int lane = threadIdx.x & 63;
        const float* rp = x + (size_t)row * D_EMB;
        float4 v0 = *(const float4*)(rp + lane * 8);
        float4 v1 = *(const float4*)(rp + lane * 8 + 4);
        float s  = v0.x + v0.y + v0.z + v0.w + v1.x + v1.y + v1.z + v1.w;
        float s2 = v0.x*v0.x + v0.y*v0.y + v0.z*v0.z + v0.w*v0.w
                 + v1.x*v1.x + v1.y*v1.y + v1.z*v1.z + v1.w*v1.w;
#pragma unroll
        for (int off = 32; off; off >>= 1) {
            s  += __shfl_xor(s,  off);
            s2 += __shfl_xor(s2, off);
        }
        float mu  = s / 512.0f;
        float var = s2 / 512.0f - mu * mu;
        float inv = 1.0f / sqrtf(var + 1e-5f);
        const float* gp = g + lane * 8;
        const float* bp = b + lane * 8;
        float o[8];
        o[0]=(v0.x-mu)*inv*gp[0]+bp[0]; o[1]=(v0.y-mu)*inv*gp[1]+bp[1];
        o[2]=(v0.z-mu)*inv*gp[2]+bp[2]; o[3]=(v0.w-mu)*inv*gp[3]+bp[3];
        o[4]=(v1.x-mu)*inv*gp[4]+bp[4]; o[5]=(v1.y-mu)*inv*gp[5]+bp[5];
        o[6]=(v1.z-mu)*inv*gp[6]+bp[6]; o[7]=(v1.w-mu)*inv*gp[7]+bp[7];
        short8 h8, l8;
#pragma unroll
        for (int j = 0; j < 8; ++j) {
            uint16_t h = f2bf(o[j]);
            h8[j] = (short)h;
            l8[j] = (short)f2bf(o[j] - bf2f(h));
        }
        size_t blk = (size_t)(row >> 4) * 16 + (lane >> 2);
        int inner  = (lane & 3) * 16 + (row & 15);
        ((short8*)xh)[blk * 64 + inner] = h8;
        ((short8*)xl)[blk * 64 + inner] = l8;
    } else {
        int blk = blockIdx.x - 2400;
        const float* W; short *hi, *lo; int K, base;
        if      (blk <  64) { W = w_in; hi = win_hi; lo = win_lo; K = 512; base = 0;   }
        else if (blk <  96) { W = wq;   hi = wq_hi;  lo = wq_lo;  K = 256; base = 64;  }
        else if (blk < 128) { W = wk;   hi = wk_hi;  lo = wk_lo;  K = 256; base = 96;  }
        else if (blk < 160) { W = wv;   hi = wv_hi;  lo = wv_lo;  K = 256; base = 128; }
        else if (blk < 192) { W = wo;   hi = wo_hi;  lo = wo_lo;  K = 256; base = 160; }
        else                { W = w1;   hi = w1a_hi; lo = w1a_lo; K = 256; base = 192; }
        int t = (blk - base) * 256 + threadIdx.x;
        int n = t & 255, k8 = t >> 8;
        short8 h8, l8;
#pragma unroll
        for (int j = 0; j < 8; ++j) {
            float wvl = W[(size_t)(k8 * 8 + j) * 256 + n];
            uint16_t h = f2bf(wvl);
            h8[j] = (short)h;
            l8[j] = (short)f2bf(wvl - bf2f(h));
        }
        size_t bb = (size_t)(n >> 4) * (K >> 5) + (k8 >> 2);
        int inner = (k8 & 3) * 16 + (n & 15);
        ((short8*)hi)[bb * 64 + inner] = h8;
        ((short8*)lo)[bb * 64 + inner] = l8;
    }
}

// ---------------- split-bf16 MFMA core: 16x32 wave tile, depth-2 rolling prefetch ----------------
template<int KB>
__device__ __forceinline__ void mm_core(const short8* __restrict__ pAh, const short8* __restrict__ pAl,
                                        const short8* __restrict__ pBh0, const short8* __restrict__ pBl0,
                                        const short8* __restrict__ pBh1, const short8* __restrict__ pBl1,
                                        f32x4& acc0, f32x4& acc1) {
    short8 ah[3], al[3], bh0[3], bl0[3], bh1[3], bl1[3];
#pragma unroll
    for (int i = 0; i < 2; ++i) {
        int off = i * 64;
        ah[i] = pAh[off];  al[i] = pAl[off];
        bh0[i] = pBh0[off]; bl0[i] = pBl0[off];
        bh1[i] = pBh1[off]; bl1[i] = pBl1[off];
    }
#pragma unroll
    for (int ks = 0; ks < KB; ++ks) {
        int cur = ks % 3;
        if (ks + 2 < KB) {
            int pre = (ks + 2) % 3, off = (ks + 2) * 64;
            ah[pre] = pAh[off];  al[pre] = pAl[off];
            bh0[pre] = pBh0[off]; bl0[pre] = pBl0[off];
            bh1[pre] = pBh1[off]; bl1[pre] = pBl1[off];
        }
        acc0 = __builtin_amdgcn_mfma_f32_16x16x32_bf16(ah[cur], bh0[cur], acc0, 0, 0, 0);
        acc0 = __builtin_amdgcn_mfma_f32_16x16x32_bf16(ah[cur], bl0[cur], acc0, 0, 0, 0);
        acc0 = __builtin_amdgcn_mfma_f32_16x16x32_bf16(al[cur], bh0[cur], acc0, 0, 0, 0);
        acc1 = __builtin_amdgcn_mfma_f32_16x16x32_bf16(ah[cur], bh1[cur], acc1, 0, 0, 0);
        acc1 = __builtin_amdgcn_mfma_f32_16x16x32_bf16(ah[cur], bl1[cur], acc1, 0, 0, 0);
        acc1 = __builtin_amdgcn_mfma_f32_16x16x32_bf16(al[cur], bh1[cur], acc1, 0, 0, 0);
    }
}

__device__ __forceinline__ void epi_store(f32x4 acc, int row0, int col, int N,
                                          float* __restrict__ Cf, short* __restrict__ Chi,
                                          short* __restrict__ Clo, int act) {
#pragma unroll
    for (int r = 0; r < 4; ++r) {
        int row = row0 + r;
        float v2 = acc[r];
        if (act)  v2 = gelu_f(v2);
        if (Cf) Cf[(size_t)row * N + col] = v2;
        if (Chi) {
            uint16_t h = f2bf(v2);
            size_t ad = swzA(row, col, 256);
            Chi[ad] = (short)h;
            Clo[ad] = (short)f2bf(v2 - bf2f(h));
        }
    }
}

// ---------------- h1 GEMM fused with noise-table generation ----------------
// grid (713, 8) in nzmode: x<150 -> GEMM blocks (dispatched first; x varies
// fastest), x>=150 -> noise units nb=(x-150)*8+y (0..4503, guard 4500).
__global__ __launch_bounds__(256) void gemm16_nz(const short8* __restrict__ Ah,
                                                 const short8* __restrict__ Al,
                                                 const short8* __restrict__ Bh,
                                                 const short8* __restrict__ Bl,
                                                 short* __restrict__ Chi,
                                                 short* __restrict__ Clo,
                                                 float* __restrict__ noise) {
    if (blockIdx.x >= 150) {
        int nb = (blockIdx.x - 150) * 8 + blockIdx.y;
        if (nb < 4500) {
            int T  = nb * 256 + threadIdx.x;          // 0..1,151,999
            int q  = T / NSAMP_T;                     // quad index 0..11
            int g2 = T - q * NSAMP_T;                 // sample id
            uint32_t cbase = (uint32_t)g2 * 48u + (uint32_t)(q * 4);
            float4 o;
            { uint32_t x0=0u, x1=cbase + 0u; threefry01(x0,x1); o.x = bits_to_normal(x0^x1) * 0.05f; }
            { uint32_t x0=0u, x1=cbase + 1u; threefry01(x0,x1); o.y = bits_to_normal(x0^x1) * 0.05f; }
            { uint32_t x0=0u, x1=cbase + 2u; threefry01(x0,x1); o.z = bits_to_normal(x0^x1) * 0.05f; }
            { uint32_t x0=0u, x1=cbase + 3u; threefry01(x0,x1); o.w = bits_to_normal(x0^x1) * 0.05f; }
            ((float4*)noise)[(size_t)q * NSAMP_T + g2] = o;
        }
        return;
    }
    int lane = threadIdx.x & 63;
    int wv   = threadIdx.x >> 6;
    int ms   = blockIdx.x * 4 + wv;
    int ns0  = blockIdx.y * 2;
    const short8* pAh  = Ah + (size_t)ms  * 16 * 64 + lane;
    const short8* pAl  = Al + (size_t)ms  * 16 * 64 + lane;
    const short8* pBh0 = Bh + (size_t)ns0 * 16 * 64 + lane;
    const short8* pBl0 = Bl + (size_t)ns0 * 16 * 64 + lane;
    const short8* pBh1 = pBh0 + (size_t)16 * 64;
    const short8* pBl1 = pBl0 + (size_t)16 * 64;
    f32x4 acc0 = {0.f,0.f,0.f,0.f}, acc1 = {0.f,0.f,0.f,0.f};
    mm_core<16>(pAh, pAl, pBh0, pBl0, pBh1, pBl1, acc0, acc1);
    int row0 = ms * 16 + (lane >> 4) * 4;
    int cin  = lane & 15;
    epi_store(acc0, row0, ns0 * 16 + cin,      256, nullptr, Chi, Clo, 1);
    epi_store(acc1, row0, (ns0 + 1) * 16 + cin, 256, nullptr, Chi, Clo, 1);
}

// fused q/k/v: grid (150, 24); matrix = blockIdx.y>>3, n-strip-pair = blockIdx.y&7
__global__ __launch_bounds__(256) void gemm_qkv(const short8* __restrict__ Ah,
                                                const short8* __restrict__ Al,
                                                const short8* __restrict__ Bhq, const short8* __restrict__ Blq,
                                                const short8* __restrict__ Bhk, const short8* __restrict__ Blk,
                                                const short8* __restrict__ Bhv, const short8* __restrict__ Blv,
                                                float* __restrict__ q, float* __restrict__ k,
                                                float* __restrict__ v) {
    int lane = threadIdx.x & 63;
    int wv   = threadIdx.x >> 6;
    int ms   = blockIdx.x * 4 + wv;
    int sel  = blockIdx.y >> 3;
    int ns0  = (blockIdx.y & 7) * 2;
    const short8* Bh = (sel == 0) ? Bhq : (sel == 1) ? Bhk : Bhv;
    const short8* Bl = (sel == 0) ? Blq : (sel == 1) ? Blk : Blv;
    float* C = (sel == 0) ? q : (sel == 1) ? k : v;
    const short8* pAh  = Ah + (size_t)ms  * 8 * 64 + lane;
    const short8* pAl  = Al + (size_t)ms  * 8 * 64 + lane;
    const short8* pBh0 = Bh + (size_t)ns0 * 8 * 64 + lane;
    const short8* pBl0 = Bl + (size_t)ns0 * 8 * 64 + lane;
    const short8* pBh1 = pBh0 + 8 * 64;
    const short8* pBl1 = pBl0 + 8 * 64;
    f32x4 acc0 = {0.f,0.f,0.f,0.f}, acc1 = {0.f,0.f,0.f,0.f};
    mm_core<8>(pAh, pAl, pBh0, pBl0, pBh1, pBl1, acc0, acc1);
    int row0 = ms * 16 + (lane >> 4) * 4;
    int cin  = lane & 15;
    epi_store(acc0, row0, ns0 * 16 + cin,      256, C, nullptr, nullptr, 0);
    epi_store(acc1, row0, (ns0 + 1) * 16 + cin, 256, C, nullptr, nullptr, 0);
}

// ---------------- attention v2: 4x4-blocked QK^T, XOR-swizzled LDS, wave-parallel softmax ----------------
// Also zero-inits pred+gmean (58,752 floats) and counts+done (110,784 ints).
#define ASLOT(r, s) ((r) * 128 + (((s) ^ (((r) >> 2) & 7)) << 2))
__global__ __launch_bounds__(256) void attn_kernel(const float* __restrict__ q,
                                                   const float* __restrict__ k,
                                                   const float* __restrict__ v,
                                                   short* __restrict__ aoh,
                                                   short* __restrict__ aol,
                                                   float* __restrict__ zbuf,
                                                   int* __restrict__ zcnt) {
    __shared__ float sQ[NTOK * 128];
    __shared__ float sK[NTOK * 128];
    __shared__ float sS[NTOK * 51];
    int blk = blockIdx.x;
    int b = blk >> 1, h = blk & 1;
    const size_t base = (size_t)b * NTOK * C_DIM + h * HD;
    int tid = threadIdx.x;
    {   // zero-init for downstream atomics (counts + done counters)
        int zi = blk * 256 + tid;
        if (zi < ROWS + B2 * C_DIM) zbuf[zi] = 0.0f;
        for (int i = zi; i < NCNT + B2; i += 384 * 256) zcnt[i] = 0;
    }
    for (int idx = tid; idx < 1600; idx += 256) {
        int r = idx >> 5, s = idx & 31;
        int ps = ASLOT(r, s);
        *(float4*)&sQ[ps] = *(const float4*)(q + base + (size_t)r * C_DIM + s * 4);
        *(float4*)&sK[ps] = *(const float4*)(k + base + (size_t)r * C_DIM + s * 4);
    }
    __syncthreads();
    if (tid < 169) {                 // 13x13 items of 4x4 dots
        int i2 = tid / 13, j2 = tid - i2 * 13;
        int i0 = i2 * 4, j0 = j2 * 4;
        int kq = i2 & 7, kk = j2 & 7;
        const float* qp[4];
        const float* kp[4];
#pragma unroll
        for (int r = 0; r < 4; ++r) {
            int ir = i0 + r; if (ir > 49) ir = 49;
            int jr = j0 + r; if (jr > 49) jr = 49;
            qp[r] = &sQ[ir * 128];
            kp[r] = &sK[jr * 128];
        }
        f32x4 acc[4][4];
#pragma unroll
        for (int r = 0; r < 4; ++r)
#pragma unroll
            for (int c = 0; c < 4; ++c) acc[r][c] = (f32x4){0.f, 0.f, 0.f, 0.f};
#pragma unroll 4
        for (int t = 0; t < 32; ++t) {
            int oq = (t ^ kq) << 2, ok = (t ^ kk) << 2;
            f32x4 qr[4], kr[4];
#pragma unroll
            for (int r = 0; r < 4; ++r) qr[r] = *(const f32x4*)(qp[r] + oq);
#pragma unroll
            for (int c = 0; c < 4; ++c) kr[c] = *(const f32x4*)(kp[c] + ok);
#pragma unroll
            for (int r = 0; r < 4; ++r)
#pragma unroll
                for (int c = 0; c < 4; ++c) acc[r][c] += qr[r] * kr[c];
        }
        const float sc = 0.08838834764831845f;   // 1/sqrt(128)
#pragma unroll
        for (int r = 0; r < 4; ++r) {
            if (i0 + r < 50) {
#pragma unroll
                for (int c = 0; c < 4; ++c) {
                    if (j0 + c < 50) {
                        f32x4 a = acc[r][c];
                        sS[(i0 + r) * 51 + (j0 + c)] = (a[0] + a[1] + a[2] + a[3]) * sc;
                    }
                }
            }
        }
    }
    __syncthreads();
    for (int idx = tid; idx < 1600; idx += 256) {   // overwrite sQ with v (swizzled)
        int r = idx >> 5, s = idx & 31;
        *(float4*)&sQ[ASLOT(r, s)] = *(const float4*)(v + base + (size_t)r * C_DIM + s * 4);
    }
    {   // wave-parallel softmax: 4 waves x 13 rows, lanes 0..49 hold one row
        int wid = tid >> 6, lane = tid & 63;
        for (int i = wid; i < NTOK; i += 4) {
            float val = (lane < NTOK) ? sS[i * 51 + lane] : -3.0e38f;
            float m = val;
#pragma unroll
            for (int off = 32; off; off >>= 1) m = fmaxf(m, __shfl_xor(m, off));
            float e2 = expf(val - m);
            float s = e2;
#pragma unroll
            for (int off = 32; off; off >>= 1) s += __shfl_xor(s, off);
            if (lane < NTOK) sS[i * 51 + lane] = e2 * (1.0f / s);
        }
    }
    __syncthreads();
    for (int e = tid; e < 416; e += 256) {   // PV: 4 rows x 4 d's per item (13x32 items)
        int i2 = e >> 5;
        int s4 = e & 31;
        int i0 = i2 * 4;
        const float* sr[4];
#pragma unroll
        for (int r = 0; r < 4; ++r) {
            int ir = i0 + r; if (ir > 49) ir = 49;
            sr[r] = &sS[ir * 51];
        }
        f32x4 acc[4];
#pragma unroll
        for (int r = 0; r < 4; ++r) acc[r] = (f32x4){0.f, 0.f, 0.f, 0.f};
        for (int j = 0; j < NTOK; ++j) {
            f32x4 v4 = *(const f32x4*)&sQ[ASLOT(j, s4)];
#pragma unroll
            for (int r = 0; r < 4; ++r) acc[r] += v4 * sr[r][j];
        }
#pragma unroll
        for (int r = 0; r < 4; ++r) {
            if (i0 + r < 50) {
                int row = b * NTOK + i0 + r;
#pragma unroll
                for (int c = 0; c < 4; ++c) {
                    int col = h * HD + s4 * 4 + c;
                    float val = acc[r][c];
                    uint16_t hh2 = f2bf(val);
                    size_t ad = swzA(row, col, 256);
                    aoh[ad] = (short)hh2;
                    aol[ad] = (short)f2bf(val - bf2f(hh2));
                }
            }
        }
    }
}
#undef ASLOT

// ---------------- h2 = ao @ wo (fp32 + swizzled) + gmean column-sum epilogue ----------------
__global__ __launch_bounds__(256) void gemm8_wo(const short8* __restrict__ Ah,
                                                const short8* __restrict__ Al,
                                                const short8* __restrict__ Bh,
                                                const short8* __restrict__ Bl,
                                                float* __restrict__ Cf,
                                                short* __restrict__ Chi,
                                                short* __restrict__ Clo,
                                                float* __restrict__ gmean) {
    int lane = threadIdx.x & 63;
    int wv   = threadIdx.x >> 6;
    int ms   = blockIdx.x * 4 + wv;
    int ns0  = blockIdx.y * 2;
    const short8* pAh  = Ah + (size_t)ms  * 8 * 64 + lane;
    const short8* pAl  = Al + (size_t)ms  * 8 * 64 + lane;
    const short8* pBh0 = Bh + (size_t)ns0 * 8 * 64 + lane;
    const short8* pBl0 = Bl + (size_t)ns0 * 8 * 64 + lane;
    const short8* pBh1 = pBh0 + 8 * 64;
    const short8* pBl1 = pBl0 + 8 * 64;
    f32x4 acc0 = {0.f,0.f,0.f,0.f}, acc1 = {0.f,0.f,0.f,0.f};
    mm_core<8>(pAh, pAl, pBh0, pBl0, pBh1, pBl1, acc0, acc1);
    int row0 = ms * 16 + (lane >> 4) * 4;
    int cin  = lane & 15;
    epi_store(acc0, row0, ns0 * 16 + cin,      256, Cf, Chi, Clo, 0);
    epi_store(acc1, row0, (ns0 + 1) * 16 + cin, 256, Cf, Chi, Clo, 0);
    // ---- gmean partial column sums ----
    int b0 = (blockIdx.x * 64) / 50;
    int nb = ((blockIdx.x * 64 + 63) / 50) - b0 + 1;     // 2 or 3
    __shared__ float red[4][3][32];                      // wave x batch x col
#pragma unroll
    for (int bi = 0; bi < 3; ++bi) {
        float p0 = 0.f, p1 = 0.f;
        if (bi < nb) {
#pragma unroll
            for (int r = 0; r < 4; ++r) {
                bool m = ((row0 + r) / 50 - b0) == bi;
                p0 += m ? acc0[r] : 0.f;
                p1 += m ? acc1[r] : 0.f;
            }
        }
        p0 += __shfl_xor(p0, 16); p0 += __shfl_xor(p0, 32);
        p1 += __shfl_xor(p1, 16); p1 += __shfl_xor(p1, 32);
        if (lane < 16) { red[wv][bi][cin] = p0; red[wv][bi][16 + cin] = p1; }
    }
    __syncthreads();
    if (threadIdx.x < nb * 32) {
        int bi = threadIdx.x >> 5, cc = threadIdx.x & 31;
        float s = (red[0][bi][cc] + red[1][bi][cc]) + (red[2][bi][cc] + red[3][bi][cc]);
        atomicAdd(&gmean[(size_t)(b0 + bi) * C_DIM + blockIdx.y * 32 + cc], s);
    }
}

// ---------------- step-8 GEMM + gw from precomputed gmean + pred = h3 @ w2 ----------------
__global__ __launch_bounds__(256) void gemm8_pred(const short8* __restrict__ Ah,
                                                  const short8* __restrict__ Al,
                                                  const short8* __restrict__ Bh,
                                                  const short8* __restrict__ Bl,
                                                  const float* __restrict__ gmean,
                                                  const float* __restrict__ w1,
                                                  const float* __restrict__ w2,
                                                  float* __restrict__ pred_raw) {
    __shared__ float sgm[3][C_DIM];
    __shared__ float sgw[3][32];
    int xb = blockIdx.x, yb = blockIdx.y;
    int d  = threadIdx.x;
    int b0 = (xb * 64) / 50;
    int nb = ((xb * 64 + 63) / 50) - b0 + 1;     // 2 or 3 batches span this row-tile
    for (int bi = 0; bi < nb; ++bi)
        sgm[bi][d] = gmean[(size_t)(b0 + bi) * C_DIM + d] * 0.02f;
    __syncthreads();
    if (d < nb * 32) {
        int bi = d >> 5, cc = d & 31;
        const float* wb = w1 + 256 * 256 + yb * 32 + cc;
        float acc = 0.f;
#pragma unroll 4
        for (int k2 = 0; k2 < C_DIM; ++k2) acc = fmaf(sgm[bi][k2], wb[(size_t)k2 * 256], acc);
        sgw[bi][cc] = acc;
    }
    __syncthreads();
    int lane = threadIdx.x & 63;
    int wv   = threadIdx.x >> 6;
    int ms   = xb * 4 + wv;
    int ns0  = yb * 2;
    const short8* pAh  = Ah + (size_t)ms  * 8 * 64 + lane;
    const short8* pAl  = Al + (size_t)ms  * 8 * 64 + lane;
    const short8* pBh0 = Bh + (size_t)ns0 * 8 * 64 + lane;
    const short8* pBl0 = Bl + (size_t)ns0 * 8 * 64 + lane;
    const short8* pBh1 = pBh0 + 8 * 64;
    const short8* pBl1 = pBl0 + 8 * 64;
    f32x4 acc0 = {0.f,0.f,0.f,0.f}, acc1 = {0.f,0.f,0.f,0.f};
    mm_core<8>(pAh, pAl, pBh0, pBl0, pBh1, pBl1, acc0, acc1);
    int row0 = ms * 16 + (lane >> 4) * 4;
    int cin  = lane & 15;
    int c0   = ns0 * 16 + cin;
    int c1   = (ns0 + 1) * 16 + cin;
    float w2a = w2[c0], w2b = w2[c1];
#pragma unroll
    for (int r = 0; r < 4; ++r) {
        int row = row0 + r;
        int bi  = row / 50 - b0;
        float v0 = gelu_f(acc0[r] + sgw[bi][cin]);
        float v1 = gelu_f(acc1[r] + sgw[bi][16 + cin]);
        float t  = v0 * w2a + v1 * w2b;
        t += __shfl_xor(t, 1); t += __shfl_xor(t, 2);
        t += __shfl_xor(t, 4); t += __shfl_xor(t, 8);
        if (cin == 0) atomicAdd(&pred_raw[row], t);
    }
}

// ---------------- topk -> counts + last-block select: grid (192 b, 4 quarters) x 256 ----------------
// R10 kept topk fast (768 blocks) but the extra select launch ate the win
// (+1 dispatch ~ +10 us on the serial chain). Fuse select via the
// last-block-finishes pattern: each quarter signals done[b] (device-scope
// atomic after threadfence); the 4th block re-reads counts via atomic loads
// (coherent across XCDs -- avoids the G16 stale-L1/L2 hazard) and runs the
// select body. Completion-based, dispatch-order-independent.
#define STEP(li) { bool gt_ = key > li; unsigned long long t_ = gt_ ? li : key; \
                   li = gt_ ? key : li; key = t_; }
#define S1  STEP(l0)
#define S2  S1  STEP(l1)
#define S3  S2  STEP(l2)
#define S4  S3  STEP(l3)
#define S5  S4  STEP(l4)
#define S6  S5  STEP(l5)
#define S7  S6  STEP(l6)
#define S8  S7  STEP(l7)
#define S9  S8  STEP(l8)
#define S10 S9  STEP(l9)
#define S11 S10 STEP(l10)
#define S12 S11 STEP(l11)

template<int NZ>
__global__ __launch_bounds__(256, 4) void topk_select(const float* __restrict__ pred,
                                                      const float4* __restrict__ nz4,
                                                      int* __restrict__ counts,
                                                      int* __restrict__ done,
                                                      const float* __restrict__ x,
                                                      float* __restrict__ out) {
    __shared__ unsigned long long sK[125][13];   // half-1 lists; +1 pad
    __shared__ float sSP[NSPA];                  // tanh'd pred row
    __shared__ float sw[TOPKK * NSPA];           // select weights (last block)
    __shared__ int sDone;
    int b   = blockIdx.x;
    int tid = threadIdx.x;
    int hh  = tid >> 7;          // 0: d=0..23;  1: d=24..47
    int sl  = tid & 127;         // sample slot (active < 125)
    int s   = blockIdx.y * 125 + sl;
    if (tid < NSPA) sSP[tid] = tanhf(pred[b * NTOK + 2 + tid]);
    __syncthreads();
    bool act = (sl < 125);

    unsigned long long l0=0ull,l1=0ull,l2=0ull,l3=0ull,l4=0ull,l5=0ull,
                       l6=0ull,l7=0ull,l8=0ull,l9=0ull,l10=0ull,l11=0ull;
    unsigned long long key;
    if (act) {
        if (NZ) {
            const float* spl = &sSP[hh * 24];
            int g = b * NSAMP + s;
            const float4* nq = nz4 + (size_t)(hh * 6) * NSAMP_T + g;
            float4 n0 = nq[0 * NSAMP_T], n1 = nq[1 * NSAMP_T], n2 = nq[2 * NSAMP_T];
            float4 n3 = nq[3 * NSAMP_T], n4 = nq[4 * NSAMP_T], n5 = nq[5 * NSAMP_T];
#define MKKEY(dd, nv) { float v_ = spl[dd] + (nv); uint32_t vb_ = __float_as_uint(v_); \
    uint32_t mono_ = (vb_ & 0x80000000u) ? ~vb_ : (vb_ | 0x80000000u); \
    key = ((unsigned long long)mono_ << 6) | (unsigned)(63 - (hh * 24 + (dd))); }
            MKKEY(0,  n0.x) S1   MKKEY(1,  n0.y) S2   MKKEY(2,  n0.z) S3   MKKEY(3,  n0.w) S4
            MKKEY(4,  n1.x) S5   MKKEY(5,  n1.y) S6   MKKEY(6,  n1.z) S7   MKKEY(7,  n1.w) S8
            MKKEY(8,  n2.x) S9   MKKEY(9,  n2.y) S10  MKKEY(10, n2.z) S11  MKKEY(11, n2.w) S12
            MKKEY(12, n3.x) S12  MKKEY(13, n3.y) S12  MKKEY(14, n3.z) S12  MKKEY(15, n3.w) S12
            MKKEY(16, n4.x) S12  MKKEY(17, n4.y) S12  MKKEY(18, n4.z) S12  MKKEY(19, n4.w) S12
            MKKEY(20, n5.x) S12  MKKEY(21, n5.y) S12  MKKEY(22, n5.z) S12  MKKEY(23, n5.w) S12
#undef MKKEY
        } else {
            uint32_t base = (uint32_t)((b * NSAMP + s) * NSPA);
            int d0 = hh * 24;
#define FBKEY(dd) { int d_ = d0 + (dd); uint32_t x0_ = 0u, x1_ = base + (uint32_t)d_; \
    threefry01(x0_, x1_); float v_ = sSP[d_] + bits_to_normal(x0_ ^ x1_) * 0.05f; \
    uint32_t vb_ = __float_as_uint(v_); \
    uint32_t mono_ = (vb_ & 0x80000000u) ? ~vb_ : (vb_ | 0x80000000u); \
    key = ((unsigned long long)mono_ << 6) | (unsigned)(63 - d_); }
            FBKEY(0)  S1   FBKEY(1)  S2   FBKEY(2)  S3   FBKEY(3)  S4
            FBKEY(4)  S5   FBKEY(5)  S6   FBKEY(6)  S7   FBKEY(7)  S8
            FBKEY(8)  S9   FBKEY(9)  S10  FBKEY(10) S11  FBKEY(11) S12
#pragma unroll 2
            for (int dd = 12; dd < 24; ++dd) { FBKEY(dd) S12 }
#undef FBKEY
        }
        if (hh == 1) {
            unsigned long long* r = sK[sl];
            r[0]=l0; r[1]=l1; r[2]=l2;  r[3]=l3;  r[4]=l4;   r[5]=l5;
            r[6]=l6; r[7]=l7; r[8]=l8;  r[9]=l9;  r[10]=l10; r[11]=l11;
        }
    }
    __syncthreads();
    if (act && hh == 0) {
        // merge top-12 of two sorted-desc lists (half-cleaner, set-exact)
        const unsigned long long* r = sK[sl];
        unsigned long long M0  = (l0  > r[11]) ? l0  : r[11];
        unsigned long long M1  = (l1  > r[10]) ? l1  : r[10];
        unsigned long long M2  = (l2  > r[9])  ? l2  : r[9];
        unsigned long long M3  = (l3  > r[8])  ? l3  : r[8];
        unsigned long long M4  = (l4  > r[7])  ? l4  : r[7];
        unsigned long long M5  = (l5  > r[6])  ? l5  : r[6];
        unsigned long long M6  = (l6  > r[5])  ? l6  : r[5];
        unsigned long long M7  = (l7  > r[4])  ? l7  : r[4];
        unsigned long long M8  = (l8  > r[3])  ? l8  : r[3];
        unsigned long long M9  = (l9  > r[2])  ? l9  : r[2];
        unsigned long long M10 = (l10 > r[1])  ? l10 : r[1];
        unsigned long long M11 = (l11 > r[0])  ? l11 : r[0];
        unsigned long long m = 0ull;
        m |= 1ull << (unsigned)(M0  & 63ull);  m |= 1ull << (unsigned)(M1  & 63ull);
        m |= 1ull << (unsigned)(M2  & 63ull);  m |= 1ull << (unsigned)(M3  & 63ull);
        m |= 1ull << (unsigned)(M4  & 63ull);  m |= 1ull << (unsigned)(M5  & 63ull);
        m |= 1ull << (unsigned)(M6  & 63ull);  m |= 1ull << (unsigned)(M7  & 63ull);
        m |= 1ull << (unsigned)(M8  & 63ull);  m |= 1ull << (unsigned)(M9  & 63ull);
        m |= 1ull << (unsigned)(M10 & 63ull);  m |= 1ull << (unsigned)(M11 & 63ull);
#define EMIT(Mi) { unsigned a_ = (unsigned)(Mi & 63ull); \
                   int kpos_ = 11 - __popcll(m & ((1ull << a_) - 1ull)); \
                   int d_ = 63 - (int)a_; \
                   atomicAdd(&counts[(b * TOPKK + kpos_) * NSPA + d_], 1); }
        EMIT(M0)  EMIT(M1)  EMIT(M2)  EMIT(M3)  EMIT(M4)  EMIT(M5)
        EMIT(M6)  EMIT(M7)  EMIT(M8)  EMIT(M9)  EMIT(M10) EMIT(M11)
#undef EMIT
    }
    __syncthreads();
    // ---- completion signal: last of the 4 quarter-blocks for b does select
    if (tid == 0) {
        __threadfence();                         // release this block's atomics
        sDone = atomicAdd(&done[b], 1);
    }
    __syncthreads();
    if (sDone != 3) return;
    __threadfence();                             // acquire other blocks' atomics
    // counts re-read via atomic loads (coherent across XCDs)
    for (int i = tid; i < TOPKK * NSPA; i += 256)
        sw[i] = (float)atomicAdd(&counts[b * TOPKK * NSPA + i], 0) * 0.002f;
    __syncthreads();
    int d = tid;   // col d and d+256
    {   // cls rows
        const float* xr0 = x + (size_t)(b * NTOK) * D_EMB;
        out[(size_t)(b * 14 + 0) * D_EMB + d]       = xr0[d];
        out[(size_t)(b * 14 + 0) * D_EMB + d + 256] = xr0[d + 256];
        out[(size_t)(b * 14 + 1) * D_EMB + d]       = xr0[D_EMB + d];
        out[(size_t)(b * 14 + 1) * D_EMB + d + 256] = xr0[D_EMB + d + 256];
    }
    float a0[TOPKK], a1[TOPKK];
#pragma unroll
    for (int k2 = 0; k2 < TOPKK; ++k2) { a0[k2] = 0.f; a1[k2] = 0.f; }
    for (int l = 0; l < NSPA; ++l) {
        const float* xr = x + (size_t)(b * NTOK + 2 + l) * D_EMB;
        float v0 = xr[d], v1 = xr[d + 256];
#pragma unroll
        for (int k2 = 0; k2 < TOPKK; ++k2) {
            float w = sw[k2 * NSPA + l];
            a0[k2] = fmaf(w, v0, a0[k2]);            // w==0 rows are exact no-ops
            a1[k2] = fmaf(w, v1, a1[k2]);
        }
    }
#pragma unroll
    for (int k2 = 0; k2 < TOPKK; ++k2) {
        out[(size_t)(b * 14 + 2 + k2) * D_EMB + d]       = a0[k2];
        out[(size_t)(b * 14 + 2 + k2) * D_EMB + d + 256] = a1[k2];
    }
}
#undef STEP
#undef S1
#undef S2
#undef S3
#undef S4
#undef S5
#undef S6
#undef S7
#undef S8
#undef S9
#undef S10
#undef S11
#undef S12

extern "C" void kernel_launch(void* const* d_in, const int* in_sizes, int n_in,
                              void* d_out, int out_size, void* d_ws, size_t ws_size,
                              hipStream_t stream) {
    const float* x    = (const float*)d_in[0];
    const float* ln_g = (const float*)d_in[1];
    const float* ln_b = (const float*)d_in[2];
    const float* w_in = (const float*)d_in[3];
    const float* wq   = (const float*)d_in[4];
    const float* wk   = (const float*)d_in[5];
    const float* wv   = (const float*)d_in[6];
    const float* wo   = (const float*)d_in[7];
    const float* w1   = (const float*)d_in[8];
    const float* w2   = (const float*)d_in[9];
    float* out = (float*)d_out;

    char* W = (char*)d_ws;
    short* xn_hi  = (short*)(W + 0);            // 9,830,400 B
    short* xn_lo  = (short*)(W + 9830400);      // 9,830,400 B
    //   region reuse after xn is dead:
    short* ao_hi  = (short*)(W + 0);            // 4,915,200
    short* ao_lo  = (short*)(W + 4915200);      // 4,915,200
    short* h2_hi  = (short*)(W + 9830400);      // 4,915,200
    short* h2_lo  = (short*)(W + 14745600);     // 4,915,200 (ends 19,660,800)
    short* h1_hi  = (short*)(W + 19660800);     // 4,915,200
    short* h1_lo  = (short*)(W + 24576000);     // 4,915,200
    int*   counts = (int*)  (W + 19660800);     // 442,368 + 768 done (reuses dead h1 after qkv)
    int*   done   = (int*)  (W + 19660800 + NCNT * 4);
    float* q      = (float*)(W + 29491200);     // 9,830,400
    float* h2f    = (float*)(W + 29491200);     // aliases q after attn
    float* k      = (float*)(W + 39321600);     // 9,830,400
    float* v      = (float*)(W + 49152000);     // 9,830,400
    short* win_hi = (short*)(W + 58982400);     // 262,144
    short* win_lo = (short*)(W + 59244544);
    short* wq_hi  = (short*)(W + 59506688);     // 131,072 each from here
    short* wq_lo  = (short*)(W + 59637760);
    short* wk_hi  = (short*)(W + 59768832);
    short* wk_lo  = (short*)(W + 59899904);
    short* wv_hi  = (short*)(W + 60030976);
    short* wv_lo  = (short*)(W + 60162048);
    short* wo_hi  = (short*)(W + 60293120);
    short* wo_lo  = (short*)(W + 60424192);
    short* w1a_hi = (short*)(W + 60555264);
    short* w1a_lo = (short*)(W + 60686336);
    float* pred   = (float*)(W + 61472768);     // 38,400 (raw; zeroed in attn)
    float* gmean  = (float*)(W + 61511168);     // 196,608 (zeroed in attn)
    float* noise  = (float*)(W + NOISE_OFF);    // 18,432,000 (noise mode only)

    const bool nzmode = ws_size >= WS_NEED;

    // 1. fused LN + weight swizzle
    prep_kernel<<<2624, 256, 0, stream>>>(x, ln_g, ln_b, xn_hi, xn_lo,
        w_in, wq, wk, wv, wo, w1,
        win_hi, win_lo, wq_hi, wq_lo, wk_hi, wk_lo, wv_hi, wv_lo,
        wo_hi, wo_lo, w1a_hi, w1a_lo);
    // 2. h1 = gelu(xn @ w_in) + noise table (noise blocks after GEMM in dispatch order)
    gemm16_nz<<<dim3(nzmode ? 713 : 150, 8), 256, 0, stream>>>(
        (const short8*)xn_hi, (const short8*)xn_lo,
        (const short8*)win_hi, (const short8*)win_lo, h1_hi, h1_lo, noise);
    // 3. fused q/k/v = h1 @ w{q,k,v}
    gemm_qkv<<<dim3(150, 24), 256, 0, stream>>>((const short8*)h1_hi, (const short8*)h1_lo,
        (const short8*)wq_hi, (const short8*)wq_lo, (const short8*)wk_hi, (const short8*)wk_lo,
        (const short8*)wv_hi, (const short8*)wv_lo, q, k, v);
    // 4. attention v2 -> swizzled ao + pred/gmean/counts/done zero-init (xn, h1 now dead)
    attn_kernel<<<B2 * 2, 256, 0, stream>>>(q, k, v, ao_hi, ao_lo, pred, counts);
    // 5. h2 = ao @ wo (fp32 into old q + swizzled) + gmean column sums
    gemm8_wo<<<dim3(150, 8), 256, 0, stream>>>((const short8*)ao_hi, (const short8*)ao_lo,
        (const short8*)wo_hi, (const short8*)wo_lo, h2f, h2_hi, h2_lo, gmean);
    // 6. pred_raw = (gelu(h2 @ w1a + gw) @ w2), gw from precomputed gmean
    gemm8_pred<<<dim3(150, 8), 256, 0, stream>>>((const short8*)h2_hi, (const short8*)h2_lo,
        (const short8*)w1a_hi, (const short8*)w1a_lo, gmean, w1, w2, pred);
    // 7. topk -> counts + last-block select (768 blocks; tanh at read)
    if (nzmode) topk_select<1><<<dim3(B2, 4), 256, 0, stream>>>(pred, (const float4*)noise, counts, done, x, out);
    else        topk_select<0><<<dim3(B2, 4), 256, 0, stream>>>(pred, nullptr, counts, done, x, out);
}

// Round 12
// 256.722 us; speedup vs baseline: 1.1188x; 1.1188x over previous
//
#include <hip/hip_runtime.h>
#include <stdint.h>

// ---------------- problem constants ----------------
#define B2      192          // 16 * MAX_FRAMES
#define NTOK    50           // tokens per frame-batch
#define ROWS    9600         // B2 * NTOK
#define D_EMB   512
#define C_DIM   256
#define HD      128          // head dim
#define NSAMP   500
#define TOPKK   12
#define NSPA    48           // 50 - SEL_DIM
#define NSAMP_T 96000        // B2 * NSAMP
#define NOISE_OFF 61953536ull
#define NOISE_BYTES 18432000ull   // 96000*48*4
#define WS_NEED (NOISE_OFF + NOISE_BYTES)

typedef short short8 __attribute__((ext_vector_type(8)));
typedef float f32x4  __attribute__((ext_vector_type(4)));

__device__ __forceinline__ float gelu_f(float x) {
    return 0.5f * x * (1.0f + erff(x * 0.7071067811865476f));
}
__device__ __forceinline__ uint16_t f2bf(float x) {   // RNE fp32->bf16
    uint32_t u = __float_as_uint(x);
    return (uint16_t)((u + 0x7fffu + ((u >> 16) & 1u)) >> 16);
}
__device__ __forceinline__ float bf2f(uint16_t b) {
    return __uint_as_float(((uint32_t)b) << 16);
}
// swizzled A-operand halfword index (frag-contiguous MFMA layout)
__device__ __forceinline__ size_t swzA(int m, int k, int K) {
    return ((size_t)(m >> 4) * (K >> 5) + (k >> 5)) * 512
         + (size_t)((((k >> 3) & 3) * 16 + (m & 15)) * 8 + (k & 7));
}

// ---------------- JAX threefry2x32 with key (0,1) ----------------
__device__ __forceinline__ uint32_t rotl32(uint32_t x, int r) {
    return (x << r) | (x >> (32 - r));
}
__device__ __forceinline__ void threefry01(uint32_t& x0, uint32_t& x1) {
    const uint32_t ks0 = 0u, ks1 = 1u, ks2 = 0x1BD11BDBu;
    x0 += ks0; x1 += ks1;
#define TFR(r) { x0 += x1; x1 = rotl32(x1, r); x1 ^= x0; }
    TFR(13) TFR(15) TFR(26) TFR(6)  x0 += ks1; x1 += ks2 + 1u;
    TFR(17) TFR(29) TFR(16) TFR(24) x0 += ks2; x1 += ks0 + 2u;
    TFR(13) TFR(15) TFR(26) TFR(6)  x0 += ks0; x1 += ks1 + 3u;
    TFR(17) TFR(29) TFR(16) TFR(24) x0 += ks1; x1 += ks2 + 4u;
    TFR(13) TFR(15) TFR(26) TFR(6)  x0 += ks2; x1 += ks0 + 5u;
#undef TFR
}

__device__ __forceinline__ float erfinv_xla(float x) {
    float w = -log1pf(-x * x);
    float p;
    if (w < 5.0f) {
        w -= 2.5f;
        p = 2.81022636e-08f;
        p = fmaf(p, w, 3.43273939e-07f);
        p = fmaf(p, w, -3.5233877e-06f);
        p = fmaf(p, w, -4.39150654e-06f);
        p = fmaf(p, w, 0.00021858087f);
        p = fmaf(p, w, -0.00125372503f);
        p = fmaf(p, w, -0.00417768164f);
        p = fmaf(p, w, 0.246640727f);
        p = fmaf(p, w, 1.50140941f);
    } else {
        w = sqrtf(w) - 3.0f;
        p = -0.000200214257f;
        p = fmaf(p, w, 0.000100950558f);
        p = fmaf(p, w, 0.00134934322f);
        p = fmaf(p, w, -0.00367342844f);
        p = fmaf(p, w, 0.00573950773f);
        p = fmaf(p, w, -0.0076224613f);
        p = fmaf(p, w, 0.00943887047f);
        p = fmaf(p, w, 1.00167406f);
        p = fmaf(p, w, 2.83297682f);
    }
    return p * x;
}

__device__ __forceinline__ float bits_to_normal(uint32_t bits) {
    float f = __uint_as_float((bits >> 9) | 0x3f800000u) - 1.0f;
    float u = f * 2.0f + (-0.99999994039535522461f);
    u = fmaxf(-0.99999994039535522461f, u);
    return 1.4142135623730951f * erfinv_xla(u);
}

// ---------------- fused LN + weight swizzle (one launch) ----------------
// blocks 0..2399: LayerNorm rows; 2400..2623: weight swizzle.
__global__ __launch_bounds__(256) void prep_kernel(const float* __restrict__ x,
                                                   const float* __restrict__ g,
                                                   const float* __restrict__ b,
                                                   short* __restrict__ xh,
                                                   short* __restrict__ xl,
                                                   const float* __restrict__ w_in, const float* __restrict__ wq,
                                                   const float* __restrict__ wk, const float* __restrict__ wv,
                                                   const float* __restrict__ wo, const float* __restrict__ w1,
                                                   short* win_hi, short* win_lo, short* wq_hi, short* wq_lo,
                                                   short* wk_hi, short* wk_lo, short* wv_hi, short* wv_lo,
                                                   short* wo_hi, short* wo_lo, short* w1a_hi, short* w1a_lo) {
    if (blockIdx.x < 2400) {
        int row  = blockIdx.x * 4 + (threadIdx.x >> 6);
        int lane = threadIdx.x & 63;
        const float* rp = x + (size_t)row * D_EMB;
        float4 v0 = *(const float4*)(rp + lane * 8);
        float4 v1 = *(const float4*)(rp + lane * 8 + 4);
        float s  = v0.x + v0.y + v0.z + v0.w + v1.x + v1.y + v1.z + v1.w;
        float s2 = v0.x*v0.x + v0.y*v0.y + v0.z*v0.z + v0.w*v0.w
                 + v1.x*v1.x + v1.y*v1.y + v1.z*v1.z + v1.w*v1.w;
#pragma unroll
        for (int off = 32; off; off >>= 1) {
            s  += __shfl_xor(s,  off);
            s2 += __shfl_xor(s2, off);
        }
        float mu  = s / 512.0f;
        float var = s2 / 512.0f - mu * mu;
        float inv = 1.0f / sqrtf(var + 1e-5f);
        const float* gp = g + lane * 8;
        const float* bp = b + lane * 8;
        float o[8];
        o[0]=(v0.x-mu)*inv*gp[0]+bp[0]; o[1]=(v0.y-mu)*inv*gp[1]+bp[1];
        o[2]=(v0.z-mu)*inv*gp[2]+bp[2]; o[3]=(v0.w-mu)*inv*gp[3]+bp[3];
        o[4]=(v1.x-mu)*inv*gp[4]+bp[4]; o[5]=(v1.y-mu)*inv*gp[5]+bp[5];
        o[6]=(v1.z-mu)*inv*gp[6]+bp[6]; o[7]=(v1.w-mu)*inv*gp[7]+bp[7];
        short8 h8, l8;
#pragma unroll
        for (int j = 0; j < 8; ++j) {
            uint16_t h = f2bf(o[j]);
            h8[j] = (short)h;
            l8[j] = (short)f2bf(o[j] - bf2f(h));
        }
        size_t blk = (size_t)(row >> 4) * 16 + (lane >> 2);
        int inner  = (lane & 3) * 16 + (row & 15);
        ((short8*)xh)[blk * 64 + inner] = h8;
        ((short8*)xl)[blk * 64 + inner] = l8;
    } else {
        int blk = blockIdx.x - 2400;
        const float* W; short *hi, *lo; int K, base;
        if      (blk <  64) { W = w_in; hi = win_hi; lo = win_lo; K = 512; base = 0;   }
        else if (blk <  96) { W = wq;   hi = wq_hi;  lo = wq_lo;  K = 256; base = 64;  }
        else if (blk < 128) { W = wk;   hi = wk_hi;  lo = wk_lo;  K = 256; base = 96;  }
        else if (blk < 160) { W = wv;   hi = wv_hi;  lo = wv_lo;  K = 256; base = 128; }
        else if (blk < 192) { W = wo;   hi = wo_hi;  lo = wo_lo;  K = 256; base = 160; }
        else                { W = w1;   hi = w1a_hi; lo = w1a_lo; K = 256; base = 192; }
        int t = (blk - base) * 256 + threadIdx.x;
        int n = t & 255, k8 = t >> 8;
        short8 h8, l8;
#pragma unroll
        for (int j = 0; j < 8; ++j) {
            float wvl = W[(size_t)(k8 * 8 + j) * 256 + n];
            uint16_t h = f2bf(wvl);
            h8[j] = (short)h;
            l8[j] = (short)f2bf(wvl - bf2f(h));
        }
        size_t bb = (size_t)(n >> 4) * (K >> 5) + (k8 >> 2);
        int inner = (k8 & 3) * 16 + (n & 15);
        ((short8*)hi)[bb * 64 + inner] = h8;
        ((short8*)lo)[bb * 64 + inner] = l8;
    }
}

// ---------------- split-bf16 MFMA core: 16x32 wave tile, depth-2 rolling prefetch ----------------
template<int KB>
__device__ __forceinline__ void mm_core(const short8* __restrict__ pAh, const short8* __restrict__ pAl,
                                        const short8* __restrict__ pBh0, const short8* __restrict__ pBl0,
                                        const short8* __restrict__ pBh1, const short8* __restrict__ pBl1,
                                        f32x4& acc0, f32x4& acc1) {
    short8 ah[3], al[3], bh0[3], bl0[3], bh1[3], bl1[3];
#pragma unroll
    for (int i = 0; i < 2; ++i) {
        int off = i * 64;
        ah[i] = pAh[off];  al[i] = pAl[off];
        bh0[i] = pBh0[off]; bl0[i] = pBl0[off];
        bh1[i] = pBh1[off]; bl1[i] = pBl1[off];
    }
#pragma unroll
    for (int ks = 0; ks < KB; ++ks) {
        int cur = ks % 3;
        if (ks + 2 < KB) {
            int pre = (ks + 2) % 3, off = (ks + 2) * 64;
            ah[pre] = pAh[off];  al[pre] = pAl[off];
            bh0[pre] = pBh0[off]; bl0[pre] = pBl0[off];
            bh1[pre] = pBh1[off]; bl1[pre] = pBl1[off];
        }
        acc0 = __builtin_amdgcn_mfma_f32_16x16x32_bf16(ah[cur], bh0[cur], acc0, 0, 0, 0);
        acc0 = __builtin_amdgcn_mfma_f32_16x16x32_bf16(ah[cur], bl0[cur], acc0, 0, 0, 0);
        acc0 = __builtin_amdgcn_mfma_f32_16x16x32_bf16(al[cur], bh0[cur], acc0, 0, 0, 0);
        acc1 = __builtin_amdgcn_mfma_f32_16x16x32_bf16(ah[cur], bh1[cur], acc1, 0, 0, 0);
        acc1 = __builtin_amdgcn_mfma_f32_16x16x32_bf16(ah[cur], bl1[cur], acc1, 0, 0, 0);
        acc1 = __builtin_amdgcn_mfma_f32_16x16x32_bf16(al[cur], bh1[cur], acc1, 0, 0, 0);
    }
}

__device__ __forceinline__ void epi_store(f32x4 acc, int row0, int col, int N,
                                          float* __restrict__ Cf, short* __restrict__ Chi,
                                          short* __restrict__ Clo, int act) {
#pragma unroll
    for (int r = 0; r < 4; ++r) {
        int row = row0 + r;
        float v2 = acc[r];
        if (act)  v2 = gelu_f(v2);
        if (Cf) Cf[(size_t)row * N + col] = v2;
        if (Chi) {
            uint16_t h = f2bf(v2);
            size_t ad = swzA(row, col, 256);
            Chi[ad] = (short)h;
            Clo[ad] = (short)f2bf(v2 - bf2f(h));
        }
    }
}

// ---------------- h1 GEMM fused with noise-table generation ----------------
// grid (713, 8) in nzmode: x<150 -> GEMM blocks (dispatched first; x varies
// fastest), x>=150 -> noise units nb=(x-150)*8+y (0..4503, guard 4500).
__global__ __launch_bounds__(256) void gemm16_nz(const short8* __restrict__ Ah,
                                                 const short8* __restrict__ Al,
                                                 const short8* __restrict__ Bh,
                                                 const short8* __restrict__ Bl,
                                                 short* __restrict__ Chi,
                                                 short* __restrict__ Clo,
                                                 float* __restrict__ noise) {
    if (blockIdx.x >= 150) {
        int nb = (blockIdx.x - 150) * 8 + blockIdx.y;
        if (nb < 4500) {
            int T  = nb * 256 + threadIdx.x;          // 0..1,151,999
            int q  = T / NSAMP_T;                     // quad index 0..11
            int g2 = T - q * NSAMP_T;                 // sample id
            uint32_t cbase = (uint32_t)g2 * 48u + (uint32_t)(q * 4);
            float4 o;
            { uint32_t x0=0u, x1=cbase + 0u; threefry01(x0,x1); o.x = bits_to_normal(x0^x1) * 0.05f; }
            { uint32_t x0=0u, x1=cbase + 1u; threefry01(x0,x1); o.y = bits_to_normal(x0^x1) * 0.05f; }
            { uint32_t x0=0u, x1=cbase + 2u; threefry01(x0,x1); o.z = bits_to_normal(x0^x1) * 0.05f; }
            { uint32_t x0=0u, x1=cbase + 3u; threefry01(x0,x1); o.w = bits_to_normal(x0^x1) * 0.05f; }
            ((float4*)noise)[(size_t)q * NSAMP_T + g2] = o;
        }
        return;
    }
    int lane = threadIdx.x & 63;
    int wv   = threadIdx.x >> 6;
    int ms   = blockIdx.x * 4 + wv;
    int ns0  = blockIdx.y * 2;
    const short8* pAh  = Ah + (size_t)ms  * 16 * 64 + lane;
    const short8* pAl  = Al + (size_t)ms  * 16 * 64 + lane;
    const short8* pBh0 = Bh + (size_t)ns0 * 16 * 64 + lane;
    const short8* pBl0 = Bl + (size_t)ns0 * 16 * 64 + lane;
    const short8* pBh1 = pBh0 + (size_t)16 * 64;
    const short8* pBl1 = pBl0 + (size_t)16 * 64;
    f32x4 acc0 = {0.f,0.f,0.f,0.f}, acc1 = {0.f,0.f,0.f,0.f};
    mm_core<16>(pAh, pAl, pBh0, pBl0, pBh1, pBl1, acc0, acc1);
    int row0 = ms * 16 + (lane >> 4) * 4;
    int cin  = lane & 15;
    epi_store(acc0, row0, ns0 * 16 + cin,      256, nullptr, Chi, Clo, 1);
    epi_store(acc1, row0, (ns0 + 1) * 16 + cin, 256, nullptr, Chi, Clo, 1);
}

// fused q/k/v: grid (150, 24); matrix = blockIdx.y>>3, n-strip-pair = blockIdx.y&7
__global__ __launch_bounds__(256) void gemm_qkv(const short8* __restrict__ Ah,
                                                const short8* __restrict__ Al,
                                                const short8* __restrict__ Bhq, const short8* __restrict__ Blq,
                                                const short8* __restrict__ Bhk, const short8* __restrict__ Blk,
                                                const short8* __restrict__ Bhv, const short8* __restrict__ Blv,
                                                float* __restrict__ q, float* __restrict__ k,
                                                float* __restrict__ v) {
    int lane = threadIdx.x & 63;
    int wv   = threadIdx.x >> 6;
    int ms   = blockIdx.x * 4 + wv;
    int sel  = blockIdx.y >> 3;
    int ns0  = (blockIdx.y & 7) * 2;
    const short8* Bh = (sel == 0) ? Bhq : (sel == 1) ? Bhk : Bhv;
    const short8* Bl = (sel == 0) ? Blq : (sel == 1) ? Blk : Blv;
    float* C = (sel == 0) ? q : (sel == 1) ? k : v;
    const short8* pAh  = Ah + (size_t)ms  * 8 * 64 + lane;
    const short8* pAl  = Al + (size_t)ms  * 8 * 64 + lane;
    const short8* pBh0 = Bh + (size_t)ns0 * 8 * 64 + lane;
    const short8* pBl0 = Bl + (size_t)ns0 * 8 * 64 + lane;
    const short8* pBh1 = pBh0 + 8 * 64;
    const short8* pBl1 = pBl0 + 8 * 64;
    f32x4 acc0 = {0.f,0.f,0.f,0.f}, acc1 = {0.f,0.f,0.f,0.f};
    mm_core<8>(pAh, pAl, pBh0, pBl0, pBh1, pBl1, acc0, acc1);
    int row0 = ms * 16 + (lane >> 4) * 4;
    int cin  = lane & 15;
    epi_store(acc0, row0, ns0 * 16 + cin,      256, C, nullptr, nullptr, 0);
    epi_store(acc1, row0, (ns0 + 1) * 16 + cin, 256, C, nullptr, nullptr, 0);
}

// ---------------- attention v2: 4x4-blocked QK^T, XOR-swizzled LDS, wave-parallel softmax ----------------
// Also zero-inits pred+gmean (contiguous 58752-float region) for the
// downstream atomics -- 384 blocks x 256 threads covers it in one shot.
#define ASLOT(r, s) ((r) * 128 + (((s) ^ (((r) >> 2) & 7)) << 2))
__global__ __launch_bounds__(256) void attn_kernel(const float* __restrict__ q,
                                                   const float* __restrict__ k,
                                                   const float* __restrict__ v,
                                                   short* __restrict__ aoh,
                                                   short* __restrict__ aol,
                                                   float* __restrict__ zbuf) {
    __shared__ float sQ[NTOK * 128];
    __shared__ float sK[NTOK * 128];
    __shared__ float sS[NTOK * 51];
    int blk = blockIdx.x;
    int b = blk >> 1, h = blk & 1;
    const size_t base = (size_t)b * NTOK * C_DIM + h * HD;
    int tid = threadIdx.x;
    {   // pred + gmean zero-init (consumed by gemm8_wo/gemm8_pred atomics later)
        int zi = blk * 256 + tid;
        if (zi < ROWS + B2 * C_DIM) zbuf[zi] = 0.0f;
    }
    for (int idx = tid; idx < 1600; idx += 256) {
        int r = idx >> 5, s = idx & 31;
        int ps = ASLOT(r, s);
        *(float4*)&sQ[ps] = *(const float4*)(q + base + (size_t)r * C_DIM + s * 4);
        *(float4*)&sK[ps] = *(const float4*)(k + base + (size_t)r * C_DIM + s * 4);
    }
    __syncthreads();
    if (tid < 169) {                 // 13x13 items of 4x4 dots
        int i2 = tid / 13, j2 = tid - i2 * 13;
        int i0 = i2 * 4, j0 = j2 * 4;
        int kq = i2 & 7, kk = j2 & 7;
        const float* qp[4];
        const float* kp[4];
#pragma unroll
        for (int r = 0; r < 4; ++r) {
            int ir = i0 + r; if (ir > 49) ir = 49;
            int jr = j0 + r; if (jr > 49) jr = 49;
            qp[r] = &sQ[ir * 128];
            kp[r] = &sK[jr * 128];
        }
        f32x4 acc[4][4];
#pragma unroll
        for (int r = 0; r < 4; ++r)
#pragma unroll
            for (int c = 0; c < 4; ++c) acc[r][c] = (f32x4){0.f, 0.f, 0.f, 0.f};
#pragma unroll 4
        for (int t = 0; t < 32; ++t) {
            int oq = (t ^ kq) << 2, ok = (t ^ kk) << 2;
            f32x4 qr[4], kr[4];
#pragma unroll
            for (int r = 0; r < 4; ++r) qr[r] = *(const f32x4*)(qp[r] + oq);
#pragma unroll
            for (int c = 0; c < 4; ++c) kr[c] = *(const f32x4*)(kp[c] + ok);
#pragma unroll
            for (int r = 0; r < 4; ++r)
#pragma unroll
                for (int c = 0; c < 4; ++c) acc[r][c] += qr[r] * kr[c];
        }
        const float sc = 0.08838834764831845f;   // 1/sqrt(128)
#pragma unroll
        for (int r = 0; r < 4; ++r) {
            if (i0 + r < 50) {
#pragma unroll
                for (int c = 0; c < 4; ++c) {
                    if (j0 + c < 50) {
                        f32x4 a = acc[r][c];
                        sS[(i0 + r) * 51 + (j0 + c)] = (a[0] + a[1] + a[2] + a[3]) * sc;
                    }
                }
            }
        }
    }
    __syncthreads();
    for (int idx = tid; idx < 1600; idx += 256) {   // overwrite sQ with v (swizzled)
        int r = idx >> 5, s = idx & 31;
        *(float4*)&sQ[ASLOT(r, s)] = *(const float4*)(v + base + (size_t)r * C_DIM + s * 4);
    }
    {   // wave-parallel softmax: 4 waves x 13 rows, lanes 0..49 hold one row
        int wid = tid >> 6, lane = tid & 63;
        for (int i = wid; i < NTOK; i += 4) {
            float val = (lane < NTOK) ? sS[i * 51 + lane] : -3.0e38f;
            float m = val;
#pragma unroll
            for (int off = 32; off; off >>= 1) m = fmaxf(m, __shfl_xor(m, off));
            float e2 = expf(val - m);
            float s = e2;
#pragma unroll
            for (int off = 32; off; off >>= 1) s += __shfl_xor(s, off);
            if (lane < NTOK) sS[i * 51 + lane] = e2 * (1.0f / s);
        }
    }
    __syncthreads();
    for (int e = tid; e < 416; e += 256) {   // PV: 4 rows x 4 d's per item (13x32 items)
        int i2 = e >> 5;
        int s4 = e & 31;
        int i0 = i2 * 4;
        const float* sr[4];
#pragma unroll
        for (int r = 0; r < 4; ++r) {
            int ir = i0 + r; if (ir > 49) ir = 49;
            sr[r] = &sS[ir * 51];
        }
        f32x4 acc[4];
#pragma unroll
        for (int r = 0; r < 4; ++r) acc[r] = (f32x4){0.f, 0.f, 0.f, 0.f};
        for (int j = 0; j < NTOK; ++j) {
            f32x4 v4 = *(const f32x4*)&sQ[ASLOT(j, s4)];
#pragma unroll
            for (int r = 0; r < 4; ++r) acc[r] += v4 * sr[r][j];
        }
#pragma unroll
        for (int r = 0; r < 4; ++r) {
            if (i0 + r < 50) {
                int row = b * NTOK + i0 + r;
#pragma unroll
                for (int c = 0; c < 4; ++c) {
                    int col = h * HD + s4 * 4 + c;
                    float val = acc[r][c];
                    uint16_t hh2 = f2bf(val);
                    size_t ad = swzA(row, col, 256);
                    aoh[ad] = (short)hh2;
                    aol[ad] = (short)f2bf(val - bf2f(hh2));
                }
            }
        }
    }
}
#undef ASLOT

// ---------------- h2 = ao @ wo (fp32 + swizzled) + gmean column-sum epilogue ----------------
// The h2 values are already in this kernel's accumulators -- reduce here:
// per-wave shfl column sums per batch segment (fixed order), cross-wave LDS
// combine, then <=2 global atomic contributions per (b,c) (commutative ->
// run-deterministic). gmean zeroed upstream in attn_kernel.
__global__ __launch_bounds__(256) void gemm8_wo(const short8* __restrict__ Ah,
                                                const short8* __restrict__ Al,
                                                const short8* __restrict__ Bh,
                                                const short8* __restrict__ Bl,
                                                float* __restrict__ Cf,
                                                short* __restrict__ Chi,
                                                short* __restrict__ Clo,
                                                float* __restrict__ gmean) {
    int lane = threadIdx.x & 63;
    int wv   = threadIdx.x >> 6;
    int ms   = blockIdx.x * 4 + wv;
    int ns0  = blockIdx.y * 2;
    const short8* pAh  = Ah + (size_t)ms  * 8 * 64 + lane;
    const short8* pAl  = Al + (size_t)ms  * 8 * 64 + lane;
    const short8* pBh0 = Bh + (size_t)ns0 * 8 * 64 + lane;
    const short8* pBl0 = Bl + (size_t)ns0 * 8 * 64 + lane;
    const short8* pBh1 = pBh0 + 8 * 64;
    const short8* pBl1 = pBl0 + 8 * 64;
    f32x4 acc0 = {0.f,0.f,0.f,0.f}, acc1 = {0.f,0.f,0.f,0.f};
    mm_core<8>(pAh, pAl, pBh0, pBl0, pBh1, pBl1, acc0, acc1);
    int row0 = ms * 16 + (lane >> 4) * 4;
    int cin  = lane & 15;
    epi_store(acc0, row0, ns0 * 16 + cin,      256, Cf, Chi, Clo, 0);
    epi_store(acc1, row0, (ns0 + 1) * 16 + cin, 256, Cf, Chi, Clo, 0);
    // ---- gmean partial column sums ----
    int b0 = (blockIdx.x * 64) / 50;
    int nb = ((blockIdx.x * 64 + 63) / 50) - b0 + 1;     // 2 or 3
    __shared__ float red[4][3][32];                      // wave x batch x col
#pragma unroll
    for (int bi = 0; bi < 3; ++bi) {
        float p0 = 0.f, p1 = 0.f;
        if (bi < nb) {
#pragma unroll
            for (int r = 0; r < 4; ++r) {
                bool m = ((row0 + r) / 50 - b0) == bi;
                p0 += m ? acc0[r] : 0.f;
                p1 += m ? acc1[r] : 0.f;
            }
        }
        p0 += __shfl_xor(p0, 16); p0 += __shfl_xor(p0, 32);
        p1 += __shfl_xor(p1, 16); p1 += __shfl_xor(p1, 32);
        if (lane < 16) { red[wv][bi][cin] = p0; red[wv][bi][16 + cin] = p1; }
    }
    __syncthreads();
    if (threadIdx.x < nb * 32) {
        int bi = threadIdx.x >> 5, cc = threadIdx.x & 31;
        float s = (red[0][bi][cc] + red[1][bi][cc]) + (red[2][bi][cc] + red[3][bi][cc]);
        atomicAdd(&gmean[(size_t)(b0 + bi) * C_DIM + blockIdx.y * 32 + cc], s);
    }
}

// ---------------- step-8 GEMM + gw from precomputed gmean + pred = h3 @ w2 ----------------
// Loads the 196 KB gmean buffer (x0.02); gw dot vs fp32 w1 is L2-resident.
// h3 never materialized; tanh applied at topk read.
__global__ __launch_bounds__(256) void gemm8_pred(const short8* __restrict__ Ah,
                                                  const short8* __restrict__ Al,
                                                  const short8* __restrict__ Bh,
                                                  const short8* __restrict__ Bl,
                                                  const float* __restrict__ gmean,
                                                  const float* __restrict__ w1,
                                                  const float* __restrict__ w2,
                                                  float* __restrict__ pred_raw) {
    __shared__ float sgm[3][C_DIM];
    __shared__ float sgw[3][32];
    int xb = blockIdx.x, yb = blockIdx.y;
    int d  = threadIdx.x;
    int b0 = (xb * 64) / 50;
    int nb = ((xb * 64 + 63) / 50) - b0 + 1;     // 2 or 3 batches span this row-tile
    for (int bi = 0; bi < nb; ++bi)
        sgm[bi][d] = gmean[(size_t)(b0 + bi) * C_DIM + d] * 0.02f;
    __syncthreads();
    if (d < nb * 32) {
        int bi = d >> 5, cc = d & 31;
        const float* wb = w1 + 256 * 256 + yb * 32 + cc;
        float acc = 0.f;
#pragma unroll 4
        for (int k2 = 0; k2 < C_DIM; ++k2) acc = fmaf(sgm[bi][k2], wb[(size_t)k2 * 256], acc);
        sgw[bi][cc] = acc;
    }
    __syncthreads();
    int lane = threadIdx.x & 63;
    int wv   = threadIdx.x >> 6;
    int ms   = xb * 4 + wv;
    int ns0  = yb * 2;
    const short8* pAh  = Ah + (size_t)ms  * 8 * 64 + lane;
    const short8* pAl  = Al + (size_t)ms  * 8 * 64 + lane;
    const short8* pBh0 = Bh + (size_t)ns0 * 8 * 64 + lane;
    const short8* pBl0 = Bl + (size_t)ns0 * 8 * 64 + lane;
    const short8* pBh1 = pBh0 + 8 * 64;
    const short8* pBl1 = pBl0 + 8 * 64;
    f32x4 acc0 = {0.f,0.f,0.f,0.f}, acc1 = {0.f,0.f,0.f,0.f};
    mm_core<8>(pAh, pAl, pBh0, pBl0, pBh1, pBl1, acc0, acc1);
    int row0 = ms * 16 + (lane >> 4) * 4;
    int cin  = lane & 15;
    int c0   = ns0 * 16 + cin;
    int c1   = (ns0 + 1) * 16 + cin;
    float w2a = w2[c0], w2b = w2[c1];
#pragma unroll
    for (int r = 0; r < 4; ++r) {
        int row = row0 + r;
        int bi  = row / 50 - b0;
        float v0 = gelu_f(acc0[r] + sgw[bi][cin]);
        float v1 = gelu_f(acc1[r] + sgw[bi][16 + cin]);
        float t  = v0 * w2a + v1 * w2b;
        t += __shfl_xor(t, 1); t += __shfl_xor(t, 2);
        t += __shfl_xor(t, 4); t += __shfl_xor(t, 8);
        if (cin == 0) atomicAdd(&pred_raw[row], t);
    }
}

// ---------------- fused topk + select: one 1024-thread block per b ----------------
// Best-measured configuration (R8: 257.9 us total). Single-compare
// compare-swap (verified bit-identical in R10).
#define STEP(li) { bool gt_ = key > li; unsigned long long t_ = gt_ ? li : key; \
                   li = gt_ ? key : li; key = t_; }
#define S1  STEP(l0)
#define S2  S1  STEP(l1)
#define S3  S2  STEP(l2)
#define S4  S3  STEP(l3)
#define S5  S4  STEP(l4)
#define S6  S5  STEP(l5)
#define S7  S6  STEP(l6)
#define S8  S7  STEP(l7)
#define S9  S8  STEP(l8)
#define S10 S9  STEP(l9)
#define S11 S10 STEP(l10)
#define S12 S11 STEP(l11)

template<int NZ>
__global__ __launch_bounds__(1024, 4) void topk_select(const float* __restrict__ pred,
                                                       const float4* __restrict__ nz4,
                                                       const float* __restrict__ x,
                                                       float* __restrict__ out) {
    __shared__ unsigned long long sK[500][13];   // half-1 lists; +1 pad (96B stride conflict)
    __shared__ int scnt[TOPKK * NSPA];           // kpos x d counts (LDS atomics)
    __shared__ float sSP[NSPA];                  // tanh'd pred row
    __shared__ int anyl[NSPA];
    int b   = blockIdx.x;
    int tid = threadIdx.x;
    int hh  = tid >> 9;          // 0: d=0..23 + kpos 0..5;  1: d=24..47 + kpos 6..11
    int s   = tid & 511;         // sample id within b (active < 500)
    for (int i = tid; i < TOPKK * NSPA; i += 1024) scnt[i] = 0;
    if (tid < NSPA) sSP[tid] = tanhf(pred[b * NTOK + 2 + tid]);
    __syncthreads();
    bool act = (s < NSAMP);

    unsigned long long l0=0ull,l1=0ull,l2=0ull,l3=0ull,l4=0ull,l5=0ull,
                       l6=0ull,l7=0ull,l8=0ull,l9=0ull,l10=0ull,l11=0ull;
    unsigned long long key;
    if (act) {
        if (NZ) {
            const float* spl = &sSP[hh * 24];
            int g = b * NSAMP + s;
            const float4* nq = nz4 + (size_t)(hh * 6) * NSAMP_T + g;
            float4 n0 = nq[0 * NSAMP_T], n1 = nq[1 * NSAMP_T], n2 = nq[2 * NSAMP_T];
            float4 n3 = nq[3 * NSAMP_T], n4 = nq[4 * NSAMP_T], n5 = nq[5 * NSAMP_T];
#define MKKEY(dd, nv) { float v_ = spl[dd] + (nv); uint32_t vb_ = __float_as_uint(v_); \
    uint32_t mono_ = (vb_ & 0x80000000u) ? ~vb_ : (vb_ | 0x80000000u); \
    key = ((unsigned long long)mono_ << 6) | (unsigned)(63 - (hh * 24 + (dd))); }
            MKKEY(0,  n0.x) S1   MKKEY(1,  n0.y) S2   MKKEY(2,  n0.z) S3   MKKEY(3,  n0.w) S4
            MKKEY(4,  n1.x) S5   MKKEY(5,  n1.y) S6   MKKEY(6,  n1.z) S7   MKKEY(7,  n1.w) S8
            MKKEY(8,  n2.x) S9   MKKEY(9,  n2.y) S10  MKKEY(10, n2.z) S11  MKKEY(11, n2.w) S12
            MKKEY(12, n3.x) S12  MKKEY(13, n3.y) S12  MKKEY(14, n3.z) S12  MKKEY(15, n3.w) S12
            MKKEY(16, n4.x) S12  MKKEY(17, n4.y) S12  MKKEY(18, n4.z) S12  MKKEY(19, n4.w) S12
            MKKEY(20, n5.x) S12  MKKEY(21, n5.y) S12  MKKEY(22, n5.z) S12  MKKEY(23, n5.w) S12
#undef MKKEY
        } else {
            uint32_t base = (uint32_t)((b * NSAMP + s) * NSPA);
            int d0 = hh * 24;
#define FBKEY(dd) { int d_ = d0 + (dd); uint32_t x0_ = 0u, x1_ = base + (uint32_t)d_; \
    threefry01(x0_, x1_); float v_ = sSP[d_] + bits_to_normal(x0_ ^ x1_) * 0.05f; \
    uint32_t vb_ = __float_as_uint(v_); \
    uint32_t mono_ = (vb_ & 0x80000000u) ? ~vb_ : (vb_ | 0x80000000u); \
    key = ((unsigned long long)mono_ << 6) | (unsigned)(63 - d_); }
            FBKEY(0)  S1   FBKEY(1)  S2   FBKEY(2)  S3   FBKEY(3)  S4
            FBKEY(4)  S5   FBKEY(5)  S6   FBKEY(6)  S7   FBKEY(7)  S8
            FBKEY(8)  S9   FBKEY(9)  S10  FBKEY(10) S11  FBKEY(11) S12
#pragma unroll 2
            for (int dd = 12; dd < 24; ++dd) { FBKEY(dd) S12 }
#undef FBKEY
        }
        if (hh == 1) {
            unsigned long long* r = sK[s];
            r[0]=l0; r[1]=l1; r[2]=l2;  r[3]=l3;  r[4]=l4;   r[5]=l5;
            r[6]=l6; r[7]=l7; r[8]=l8;  r[9]=l9;  r[10]=l10; r[11]=l11;
        }
    }
    __syncthreads();
    if (act && hh == 0) {
        // merge top-12 of two sorted-desc lists (half-cleaner, set-exact)
        const unsigned long long* r = sK[s];
        unsigned long long M0  = (l0  > r[11]) ? l0  : r[11];
        unsigned long long M1  = (l1  > r[10]) ? l1  : r[10];
        unsigned long long M2  = (l2  > r[9])  ? l2  : r[9];
        unsigned long long M3  = (l3  > r[8])  ? l3  : r[8];
        unsigned long long M4  = (l4  > r[7])  ? l4  : r[7];
        unsigned long long M5  = (l5  > r[6])  ? l5  : r[6];
        unsigned long long M6  = (l6  > r[5])  ? l6  : r[5];
        unsigned long long M7  = (l7  > r[4])  ? l7  : r[4];
        unsigned long long M8  = (l8  > r[3])  ? l8  : r[3];
        unsigned long long M9  = (l9  > r[2])  ? l9  : r[2];
        unsigned long long M10 = (l10 > r[1])  ? l10 : r[1];
        unsigned long long M11 = (l11 > r[0])  ? l11 : r[0];
        unsigned long long m = 0ull;
        m |= 1ull << (unsigned)(M0  & 63ull);  m |= 1ull << (unsigned)(M1  & 63ull);
        m |= 1ull << (unsigned)(M2  & 63ull);  m |= 1ull << (unsigned)(M3  & 63ull);
        m |= 1ull << (unsigned)(M4  & 63ull);  m |= 1ull << (unsigned)(M5  & 63ull);
        m |= 1ull << (unsigned)(M6  & 63ull);  m |= 1ull << (unsigned)(M7  & 63ull);
        m |= 1ull << (unsigned)(M8  & 63ull);  m |= 1ull << (unsigned)(M9  & 63ull);
        m |= 1ull << (unsigned)(M10 & 63ull);  m |= 1ull << (unsigned)(M11 & 63ull);
#define EMIT(Mi) { unsigned a_ = (unsigned)(Mi & 63ull); \
                   int kpos_ = 11 - __popcll(m & ((1ull << a_) - 1ull)); \
                   int d_ = 63 - (int)a_; \
                   atomicAdd(&scnt[kpos_ * NSPA + d_], 1); }
        EMIT(M0)  EMIT(M1)  EMIT(M2)  EMIT(M3)  EMIT(M4)  EMIT(M5)
        EMIT(M6)  EMIT(M7)  EMIT(M8)  EMIT(M9)  EMIT(M10) EMIT(M11)
#undef EMIT
    }
    __syncthreads();
    if (tid < NSPA) {
        int a = 0;
#pragma unroll
        for (int k2 = 0; k2 < TOPKK; ++k2) a |= scnt[k2 * NSPA + tid];
        anyl[tid] = a;
    }
    __syncthreads();
    // ---- select phase: hh=0 -> cls rows + kpos 0..5; hh=1 -> kpos 6..11; col = s
    if (hh == 0) {
        const float* xr0 = x + (size_t)(b * NTOK) * D_EMB;
        out[(size_t)(b * 14 + 0) * D_EMB + s] = xr0[s];
        out[(size_t)(b * 14 + 1) * D_EMB + s] = xr0[D_EMB + s];
    }
    float a0, a1, a2, a3, a4, a5;
    a0 = a1 = a2 = a3 = a4 = a5 = 0.f;
    int k0 = hh * 6;
    for (int l = 0; l < NSPA; ++l) {
        if (!anyl[l]) continue;                      // wave-uniform (LDS broadcast)
        float v = x[((size_t)(b * NTOK + 2 + l)) * D_EMB + s];
        a0 = fmaf((float)scnt[(k0 + 0) * NSPA + l] * 0.002f, v, a0);
        a1 = fmaf((float)scnt[(k0 + 1) * NSPA + l] * 0.002f, v, a1);
        a2 = fmaf((float)scnt[(k0 + 2) * NSPA + l] * 0.002f, v, a2);
        a3 = fmaf((float)scnt[(k0 + 3) * NSPA + l] * 0.002f, v, a3);
        a4 = fmaf((float)scnt[(k0 + 4) * NSPA + l] * 0.002f, v, a4);
        a5 = fmaf((float)scnt[(k0 + 5) * NSPA + l] * 0.002f, v, a5);
    }
    out[(size_t)(b * 14 + 2 + k0 + 0) * D_EMB + s] = a0;
    out[(size_t)(b * 14 + 2 + k0 + 1) * D_EMB + s] = a1;
    out[(size_t)(b * 14 + 2 + k0 + 2) * D_EMB + s] = a2;
    out[(size_t)(b * 14 + 2 + k0 + 3) * D_EMB + s] = a3;
    out[(size_t)(b * 14 + 2 + k0 + 4) * D_EMB + s] = a4;
    out[(size_t)(b * 14 + 2 + k0 + 5) * D_EMB + s] = a5;
}
#undef STEP
#undef S1
#undef S2
#undef S3
#undef S4
#undef S5
#undef S6
#undef S7
#undef S8
#undef S9
#undef S10
#undef S11
#undef S12

extern "C" void kernel_launch(void* const* d_in, const int* in_sizes, int n_in,
                              void* d_out, int out_size, void* d_ws, size_t ws_size,
                              hipStream_t stream) {
    const float* x    = (const float*)d_in[0];
    const float* ln_g = (const float*)d_in[1];
    const float* ln_b = (const float*)d_in[2];
    const float* w_in = (const float*)d_in[3];
    const float* wq   = (const float*)d_in[4];
    const float* wk   = (const float*)d_in[5];
    const float* wv   = (const float*)d_in[6];
    const float* wo   = (const float*)d_in[7];
    const float* w1   = (const float*)d_in[8];
    const float* w2   = (const float*)d_in[9];
    float* out = (float*)d_out;

    char* W = (char*)d_ws;
    short* xn_hi  = (short*)(W + 0);            // 9,830,400 B
    short* xn_lo  = (short*)(W + 9830400);      // 9,830,400 B
    //   region reuse after xn is dead:
    short* ao_hi  = (short*)(W + 0);            // 4,915,200
    short* ao_lo  = (short*)(W + 4915200);      // 4,915,200
    short* h2_hi  = (short*)(W + 9830400);      // 4,915,200
    short* h2_lo  = (short*)(W + 14745600);     // 4,915,200
    short* h1_hi  = (short*)(W + 19660800);     // 4,915,200
    short* h1_lo  = (short*)(W + 24576000);     // 4,915,200
    float* q      = (float*)(W + 29491200);     // 9,830,400
    float* h2f    = (float*)(W + 29491200);     // aliases q after attn
    float* k      = (float*)(W + 39321600);     // 9,830,400
    float* v      = (float*)(W + 49152000);     // 9,830,400
    short* win_hi = (short*)(W + 58982400);     // 262,144
    short* win_lo = (short*)(W + 59244544);
    short* wq_hi  = (short*)(W + 59506688);     // 131,072 each from here
    short* wq_lo  = (short*)(W + 59637760);
    short* wk_hi  = (short*)(W + 59768832);
    short* wk_lo  = (short*)(W + 59899904);
    short* wv_hi  = (short*)(W + 60030976);
    short* wv_lo  = (short*)(W + 60162048);
    short* wo_hi  = (short*)(W + 60293120);
    short* wo_lo  = (short*)(W + 60424192);
    short* w1a_hi = (short*)(W + 60555264);
    short* w1a_lo = (short*)(W + 60686336);
    float* pred   = (float*)(W + 61472768);     // 38,400 (raw; zeroed in attn)
    float* gmean  = (float*)(W + 61511168);     // 196,608 (zeroed in attn; atomic-accumulated in gemm8_wo)
    float* noise  = (float*)(W + NOISE_OFF);    // 18,432,000 (noise mode only)

    const bool nzmode = ws_size >= WS_NEED;

    // 1. fused LN + weight swizzle
    prep_kernel<<<2624, 256, 0, stream>>>(x, ln_g, ln_b, xn_hi, xn_lo,
        w_in, wq, wk, wv, wo, w1,
        win_hi, win_lo, wq_hi, wq_lo, wk_hi, wk_lo, wv_hi, wv_lo,
        wo_hi, wo_lo, w1a_hi, w1a_lo);
    // 2. h1 = gelu(xn @ w_in) + noise table (noise blocks after GEMM in dispatch order)
    gemm16_nz<<<dim3(nzmode ? 713 : 150, 8), 256, 0, stream>>>(
        (const short8*)xn_hi, (const short8*)xn_lo,
        (const short8*)win_hi, (const short8*)win_lo, h1_hi, h1_lo, noise);
    // 3. fused q/k/v = h1 @ w{q,k,v}
    gemm_qkv<<<dim3(150, 24), 256, 0, stream>>>((const short8*)h1_hi, (const short8*)h1_lo,
        (const short8*)wq_hi, (const short8*)wq_lo, (const short8*)wk_hi, (const short8*)wk_lo,
        (const short8*)wv_hi, (const short8*)wv_lo, q, k, v);
    // 4. attention v2 -> swizzled ao + pred/gmean zero-init (xn region now dead)
    attn_kernel<<<B2 * 2, 256, 0, stream>>>(q, k, v, ao_hi, ao_lo, pred);
    // 5. h2 = ao @ wo (fp32 into old q + swizzled) + gmean column sums
    gemm8_wo<<<dim3(150, 8), 256, 0, stream>>>((const short8*)ao_hi, (const short8*)ao_lo,
        (const short8*)wo_hi, (const short8*)wo_lo, h2f, h2_hi, h2_lo, gmean);
    // 6. pred_raw = (gelu(h2 @ w1a + gw) @ w2), gw from precomputed gmean
    gemm8_pred<<<dim3(150, 8), 256, 0, stream>>>((const short8*)h2_hi, (const short8*)h2_lo,
        (const short8*)w1a_hi, (const short8*)w1a_lo, gmean, w1, w2, pred);
    // 7. fused topk + select (counts in LDS; tanh at read)
    if (nzmode) topk_select<1><<<B2, 1024, 0, stream>>>(pred, (const float4*)noise, x, out);
    else        topk_select<0><<<B2, 1024, 0, stream>>>(pred, nullptr, x, out);
}